// Round 3
// baseline (1003.495 us; speedup 1.0000x reference)
//
#include <hip/hip_runtime.h>
#include <stdint.h>

typedef __attribute__((ext_vector_type(8))) short bf16x8;
typedef __attribute__((ext_vector_type(8))) unsigned short u16x8;
typedef __attribute__((ext_vector_type(4))) float f32x4;
typedef __attribute__((ext_vector_type(2))) float f32x2;

#define NB   16
#define CIN  256
#define COUT 256
#define HH   128
#define WW   128
#define SDIM 512

#define BM 256
#define BN 128
#define BK 64
#define KPAD 72        // 64 + 8 pad -> 144B row pitch = 36 dwords -> 2-way bank alias (free)
#define NCOL 130       // cols -1..128 (col 0 and 129 are the always-zero w-padding)

#define A_BYTES (BM * KPAD * 2)          // 36864
#define B_BYTES (3 * NCOL * KPAD * 2)    // 56160
#define S_BYTES (COUT * 4)               // 1024
#define LDS_BYTES (A_BYTES + B_BYTES + S_BYTES)  // 94048

__device__ __forceinline__ unsigned short f2bf(float f) {
    unsigned int u = __float_as_uint(f);
    u += 0x7fff + ((u >> 16) & 1);   // round-to-nearest-even
    return (unsigned short)(u >> 16);
}

// s[b,co] = dot(style[b,:], fc_w[co,:]) + fc_b[co]
__global__ void style_fc_kernel(const float* __restrict__ style,
                                const float* __restrict__ fc_w,
                                const float* __restrict__ fc_b,
                                float* __restrict__ s_out) {
    const int b = blockIdx.x;
    const int co = threadIdx.x;
    const f32x4* st = (const f32x4*)(style + b * SDIM);
    const f32x4* w  = (const f32x4*)(fc_w + co * SDIM);
    float acc = fc_b[co];
    #pragma unroll 4
    for (int k = 0; k < SDIM / 4; ++k) {
        f32x4 a = st[k], c = w[k];
        acc += a.x * c.x + a.y * c.y + a.z * c.z + a.w * c.w;
    }
    s_out[b * COUT + co] = acc;
}

// conv_w (Cout,Cin,3,3) f32  ->  wt[t][q][co][k] bf16, t=kh*3+kw, q=ci>>6, k=ci&63
__global__ void wt_transform_kernel(const float* __restrict__ conv_w,
                                    unsigned short* __restrict__ wt) {
    const int tid = blockIdx.x * blockDim.x + threadIdx.x;  // 65536
    const int co = tid >> 8;
    const int ci = tid & 255;
    const float* src = conv_w + (co * CIN + ci) * 9;
    const int q = ci >> 6;
    const int kl = ci & 63;
    #pragma unroll
    for (int t = 0; t < 9; ++t) {
        wt[(((t * 4 + q) * COUT + co) << 6) + kl] = f2bf(src[t]);
    }
}

// One block per (b,h): computes out[b, 0:256, h, 0:128].
// A = W[co][k] (bf16), B = x patches [k][w] (bf16, transposed in LDS), D = A*B.
__global__ void __launch_bounds__(512, 2)
modconv_kernel(const float* __restrict__ x,
               const unsigned short* __restrict__ wt,
               const float* __restrict__ s,
               float* __restrict__ out) {
    extern __shared__ char lds[];
    unsigned short* Al = (unsigned short*)lds;               // [BM][KPAD]
    unsigned short* Bl = (unsigned short*)(lds + A_BYTES);   // [3][NCOL][KPAD]
    float* Sl = (float*)(lds + A_BYTES + B_BYTES);           // [COUT]

    const int tid  = threadIdx.x;
    const int lane = tid & 63;
    const int wid  = tid >> 6;
    const int bb   = blockIdx.x >> 7;
    const int h    = blockIdx.x & 127;

    // zero B tile (covers the w-padding cols, the h-padding rows, and k-pads)
    {
        f32x4 z = {0.f, 0.f, 0.f, 0.f};
        for (int i = tid; i < B_BYTES / 16; i += 512)
            *(f32x4*)(lds + A_BYTES + i * 16) = z;
    }
    if (tid < COUT) Sl[tid] = s[bb * COUT + tid];
    __syncthreads();

    f32x4 acc[4][4];
    {
        f32x4 z = {0.f, 0.f, 0.f, 0.f};
        #pragma unroll
        for (int mi = 0; mi < 4; ++mi)
            #pragma unroll
            for (int nj = 0; nj < 4; ++nj)
                acc[mi][nj] = z;
    }

    const int wm = wid >> 1;          // 0..3 -> co quadrant
    const int wn = wid & 1;           // 0..1 -> w half
    const int cobase = wm * 64;
    const int wbase  = wn * 64;
    const int l15 = lane & 15;
    const int kl8 = (lane >> 4) * 8;

    const int p = tid & 63;           // w column-pair for B staging
    const int g = wid;                // ci group of 8 for B staging

    #pragma unroll 1
    for (int q = 0; q < 4; ++q) {
        // ---- stage B chunk q: rows h-1,h,h+1, cols 0..127 (image w), 64 ci ----
        #pragma unroll
        for (int kh = 0; kh < 3; ++kh) {
            const int r = h + kh - 1;
            if (r >= 0 && r < HH) {   // block-uniform branch
                const float* xr = x + (((size_t)(bb * CIN + q * 64 + g * 8) * HH + r) * WW) + p * 2;
                u16x8 v0, v1;
                #pragma unroll
                for (int j = 0; j < 8; ++j) {
                    f32x2 v = *(const f32x2*)(xr + j * (HH * WW));
                    v0[j] = f2bf(v.x);
                    v1[j] = f2bf(v.y);
                }
                unsigned short* d = Bl + (kh * NCOL + 1 + p * 2) * KPAD + g * 8;
                *(u16x8*)d = v0;
                *(u16x8*)(d + KPAD) = v1;
            }
        }
        // ---- loop taps; A tile re-staged per tap ----
        #pragma unroll 1
        for (int t = 0; t < 9; ++t) {
            const unsigned short* wsrc = wt + (t * 4 + q) * (BM * 64);
            #pragma unroll
            for (int it = 0; it < 4; ++it) {
                const int c = it * 512 + tid;       // 16B chunk id, 0..2047
                const int co = c >> 3;
                const int sub = c & 7;
                u16x8 v = *(const u16x8*)(wsrc + c * 8);
                *(u16x8*)(Al + co * KPAD + sub * 8) = v;
            }
            __syncthreads();

            const int kh = t / 3;
            const int kw = t - kh * 3;
            #pragma unroll
            for (int kk = 0; kk < BK; kk += 32) {
                bf16x8 a[4], b[4];
                #pragma unroll
                for (int mi = 0; mi < 4; ++mi)
                    a[mi] = *(const bf16x8*)(Al + (cobase + mi * 16 + l15) * KPAD + kk + kl8);
                #pragma unroll
                for (int nj = 0; nj < 4; ++nj)
                    b[nj] = *(const bf16x8*)(Bl + (kh * NCOL + wbase + nj * 16 + l15 + kw) * KPAD + kk + kl8);
                #pragma unroll
                for (int mi = 0; mi < 4; ++mi)
                    #pragma unroll
                    for (int nj = 0; nj < 4; ++nj)
                        acc[mi][nj] = __builtin_amdgcn_mfma_f32_16x16x32_bf16(
                            a[mi], b[nj], acc[mi][nj], 0, 0, 0);
            }
            __syncthreads();
        }
    }

    // ---- epilogue: scale by s[b,co], store f32 ----
    const int rowD = (lane >> 4) * 4;
    #pragma unroll
    for (int mi = 0; mi < 4; ++mi) {
        #pragma unroll
        for (int r = 0; r < 4; ++r) {
            const int co = cobase + mi * 16 + rowD + r;
            const float sv = Sl[co];
            float* orow = out + (((size_t)(bb * COUT + co) * HH + h) * WW);
            #pragma unroll
            for (int nj = 0; nj < 4; ++nj)
                orow[wbase + nj * 16 + l15] = acc[mi][nj][r] * sv;
        }
    }
}

extern "C" void kernel_launch(void* const* d_in, const int* in_sizes, int n_in,
                              void* d_out, int out_size, void* d_ws, size_t ws_size,
                              hipStream_t stream) {
    const float* x      = (const float*)d_in[0];
    const float* style  = (const float*)d_in[1];
    const float* conv_w = (const float*)d_in[2];
    const float* fc_w   = (const float*)d_in[3];
    const float* fc_b   = (const float*)d_in[4];
    float* out = (float*)d_out;

    float* s_ws = (float*)d_ws;                                   // 16*256 f32 = 16 KB
    unsigned short* wt = (unsigned short*)((char*)d_ws + 16384);  // 9*4*256*64 bf16 = 1.125 MB

    hipFuncSetAttribute(reinterpret_cast<const void*>(modconv_kernel),
                        hipFuncAttributeMaxDynamicSharedMemorySize, LDS_BYTES);

    style_fc_kernel<<<NB, COUT, 0, stream>>>(style, fc_w, fc_b, s_ws);
    wt_transform_kernel<<<(COUT * CIN) / 256, 256, 0, stream>>>(conv_w, wt);
    modconv_kernel<<<NB * HH, 512, LDS_BYTES, stream>>>(x, wt, s_ws, out);
}

// Round 5
// 950.860 us; speedup vs baseline: 1.0554x; 1.0554x over previous
//
#include <hip/hip_runtime.h>
#include <stdint.h>

typedef __attribute__((ext_vector_type(8))) short bf16x8;
typedef __attribute__((ext_vector_type(8))) unsigned short u16x8;
typedef __attribute__((ext_vector_type(4))) float f32x4;

#define NB   16
#define CIN  256
#define COUT 256
#define HH   128
#define WW   128
#define SDIM 512

#define BK 64
#define KPAD 72        // row pitch 144B = 36 dwords; b128 reads across rows: 2-way alias (free)
#define NCOL 130       // cols -1..128 (col 0 and 129 = always-zero w-padding)

#define B_BYTES (3 * NCOL * KPAD * 2)    // 56160
#define S_BYTES (COUT * 4)               // 1024
#define LDS_BYTES (B_BYTES + S_BYTES)    // 57184  -> 2 blocks/CU

__device__ __forceinline__ unsigned short f2bf(float f) {
    unsigned int u = __float_as_uint(f);
    u += 0x7fff + ((u >> 16) & 1);   // round-to-nearest-even
    return (unsigned short)(u >> 16);
}

// s[b,co] = dot(style[b,:], fc_w[co,:]) + fc_b[co]
__global__ void style_fc_kernel(const float* __restrict__ style,
                                const float* __restrict__ fc_w,
                                const float* __restrict__ fc_b,
                                float* __restrict__ s_out) {
    const int b = blockIdx.x;
    const int co = threadIdx.x;
    const f32x4* st = (const f32x4*)(style + b * SDIM);
    const f32x4* w  = (const f32x4*)(fc_w + co * SDIM);
    float acc = fc_b[co];
    #pragma unroll 4
    for (int k = 0; k < SDIM / 4; ++k) {
        f32x4 a = st[k], c = w[k];
        acc += a.x * c.x + a.y * c.y + a.z * c.z + a.w * c.w;
    }
    s_out[b * COUT + co] = acc;
}

// conv_w (Cout,Cin,3,3) f32 -> wt[t][q][co][k] bf16 (t=kh*3+kw, q=ci>>6, k=ci&63)
// One block per co; LDS transpose; 128B-contiguous dword stores.
__global__ void wt_transform_kernel(const float* __restrict__ conv_w,
                                    unsigned short* __restrict__ wt) {
    __shared__ unsigned short T[9][256];          // [t][ci] for this co
    const int co = blockIdx.x;
    const int ci = threadIdx.x;                   // 256 threads
    const float* src = conv_w + ((size_t)co * CIN + ci) * 9;
    float v[9];
    #pragma unroll
    for (int t = 0; t < 9; ++t) v[t] = src[t];    // coalesced-ish (full lines used)
    #pragma unroll
    for (int t = 0; t < 9; ++t) T[t][ci] = f2bf(v[t]);
    __syncthreads();
    // out32[((t*4+q)*256 + co)*32 + d] = T32[(t*4+q)*32 + d]  (T row t = [q][kl] contiguous)
    const unsigned int* T32 = (const unsigned int*)&T[0][0];   // 1152 dwords
    unsigned int* out32 = (unsigned int*)wt;
    for (int idx = ci; idx < 1152; idx += 256) {
        const int d = idx & 31;
        const int r = idx >> 5;                   // r = t*4+q, 0..35
        out32[(((size_t)r * COUT + co) << 5) + d] = T32[idx];
    }
}

// One block per (b,h): out[b, 0:256, h, 0:128].
// B (x patches) staged in LDS; A (weights) loaded global->VGPR per tap (L2-resident).
__global__ void __launch_bounds__(512, 4)
modconv_kernel(const float* __restrict__ x,
               const unsigned short* __restrict__ wt,
               const float* __restrict__ s,
               float* __restrict__ out) {
    extern __shared__ char lds[];
    unsigned short* Bl = (unsigned short*)lds;         // [3][NCOL][KPAD]
    float* Sl = (float*)(lds + B_BYTES);               // [COUT]

    const int tid  = threadIdx.x;
    const int lane = tid & 63;
    const int wid  = tid >> 6;
    // XCD-aware swizzle (2048 blocks % 8 == 0 -> bijective): consecutive h on same XCD
    const int bid  = blockIdx.x;
    const int nid  = (bid & 7) * 256 + (bid >> 3);
    const int bb   = nid >> 7;
    const int h    = nid & 127;

    // zero B tile (covers w-pad cols, h-pad rows, k-pad tail)
    {
        f32x4 z = {0.f, 0.f, 0.f, 0.f};
        for (int i = tid; i < B_BYTES / 16; i += 512)
            *(f32x4*)(lds + i * 16) = z;
    }
    if (tid < COUT) Sl[tid] = s[bb * COUT + tid];

    f32x4 acc[4][4];
    {
        f32x4 z = {0.f, 0.f, 0.f, 0.f};
        #pragma unroll
        for (int mi = 0; mi < 4; ++mi)
            #pragma unroll
            for (int nj = 0; nj < 4; ++nj)
                acc[mi][nj] = z;
    }

    const int wm = wid >> 1;          // co quadrant
    const int wn = wid & 1;           // w half
    const int cobase = wm * 64;
    const int wbase  = wn * 64;
    const int l15 = lane & 15;
    const int kl8 = (lane >> 4) * 8;

    __syncthreads();                  // zero + Sl visible before staging

    #pragma unroll 1
    for (int q = 0; q < 4; ++q) {
        if (q) __syncthreads();       // all waves done reading B of q-1
        // ---- stage B chunk q: lane=col, wid=ci-octet; write banks (w+g) mod 8: minimal ----
        #pragma unroll
        for (int kh = 0; kh < 3; ++kh) {
            const int r = h + kh - 1;
            if (r >= 0 && r < HH) {   // block-uniform
                const float* xs = x + (((size_t)(bb * CIN + q * 64 + wid * 8)) * HH + r) * WW;
                #pragma unroll
                for (int half = 0; half < 2; ++half) {
                    const int w = lane + half * 64;
                    u16x8 vv;
                    #pragma unroll
                    for (int j = 0; j < 8; ++j)
                        vv[j] = f2bf(xs[j * (HH * WW) + w]);   // coalesced 256B/wave/load
                    *(u16x8*)(Bl + (kh * NCOL + 1 + w) * KPAD + wid * 8) = vv;
                }
            }
        }
        __syncthreads();              // B ready; 9 taps read-only below
        // ---- taps: A direct global->reg (no LDS, no per-tap barrier) ----
        #pragma unroll 3
        for (int t = 0; t < 9; ++t) {
            const int kh = t / 3;
            const int kw = t - kh * 3;
            const unsigned short* wsrc = wt + ((size_t)(t * 4 + q) * COUT + cobase) * 64;
            #pragma unroll
            for (int kkid = 0; kkid < 2; ++kkid) {
                const int kk = kkid * 32;
                bf16x8 a[4], b[4];
                #pragma unroll
                for (int mi = 0; mi < 4; ++mi)
                    a[mi] = *(const bf16x8*)(wsrc + (mi * 16 + l15) * 64 + kk + kl8);
                #pragma unroll
                for (int nj = 0; nj < 4; ++nj)
                    b[nj] = *(const bf16x8*)(Bl + (kh * NCOL + wbase + nj * 16 + l15 + kw) * KPAD + kk + kl8);
                #pragma unroll
                for (int mi = 0; mi < 4; ++mi)
                    #pragma unroll
                    for (int nj = 0; nj < 4; ++nj)
                        acc[mi][nj] = __builtin_amdgcn_mfma_f32_16x16x32_bf16(
                            a[mi], b[nj], acc[mi][nj], 0, 0, 0);
            }
        }
    }

    // ---- epilogue: scale by s[b,co], store f32 ----
    const int rowD = (lane >> 4) * 4;
    #pragma unroll
    for (int mi = 0; mi < 4; ++mi) {
        #pragma unroll
        for (int r = 0; r < 4; ++r) {
            const int co = cobase + mi * 16 + rowD + r;
            const float sv = Sl[co];
            float* orow = out + (((size_t)(bb * COUT + co) * HH + h) * WW);
            #pragma unroll
            for (int nj = 0; nj < 4; ++nj)
                orow[wbase + nj * 16 + l15] = acc[mi][nj][r] * sv;
        }
    }
}

extern "C" void kernel_launch(void* const* d_in, const int* in_sizes, int n_in,
                              void* d_out, int out_size, void* d_ws, size_t ws_size,
                              hipStream_t stream) {
    const float* x      = (const float*)d_in[0];
    const float* style  = (const float*)d_in[1];
    const float* conv_w = (const float*)d_in[2];
    const float* fc_w   = (const float*)d_in[3];
    const float* fc_b   = (const float*)d_in[4];
    float* out = (float*)d_out;

    float* s_ws = (float*)d_ws;                                   // 16KB
    unsigned short* wt = (unsigned short*)((char*)d_ws + 16384);  // 1.125 MB

    style_fc_kernel<<<NB, COUT, 0, stream>>>(style, fc_w, fc_b, s_ws);
    wt_transform_kernel<<<COUT, 256, 0, stream>>>(conv_w, wt);
    modconv_kernel<<<NB * HH, 512, LDS_BYTES, stream>>>(x, wt, s_ws, out);
}